// Round 20
// baseline (176.571 us; speedup 1.0000x reference)
//
#include <hip/hip_runtime.h>
#include <math.h>

typedef _Float16 f16;
typedef f16 f16x2 __attribute__((ext_vector_type(2)));
typedef f16 f16x4 __attribute__((ext_vector_type(4)));

__device__ __forceinline__ float dot2acc(f16x2 a, f16x2 b, float c){
#if __has_builtin(__builtin_amdgcn_fdot2)
  return __builtin_amdgcn_fdot2(a, b, c, false);
#else
  return c + (float)a[0]*(float)b[0] + (float)a[1]*(float)b[1];
#endif
}

// ---------------- conv1: 12->3, 3x3, s1, SAME -> c1 (f16) ----------------
// (unchanged from R18/R19; launched TWICE this round as an in-band timing probe)
__global__ __launch_bounds__(256) void k_conv1(const float* __restrict__ img,
    const float* __restrict__ cw, const float* __restrict__ cb,
    f16* __restrict__ c1h){
  int b = blockIdx.y, ty = blockIdx.x;     // ty 0..39 -> rows [5ty,5ty+5)
  int t = threadIdx.x, lane = t & 63, wv = t >> 6;
  int y0 = ty*5;

  __shared__ __align__(16) float sbuf[2][3072];   // 768 float4 (700 used + pad)

  int goff[3];
  #pragma unroll
  for (int j=0;j<3;++j){
    int k = wv + 4*j;
    int e = k*64 + lane; if (e > 699) e = 699;   // pad lanes load valid data
    int ch = e/350, rem = e - 350*ch;
    int lr = rem/50, c4 = rem - 50*lr;
    int gy = y0 - 1 + lr; gy = gy < 0 ? 0 : (gy > 199 ? 199 : gy);
    goff[j] = ch*40000 + gy*200 + c4*4;
  }
  const float* cbase0 = img + (size_t)b*480000;

  int cg = t % 50, r = t / 50;             // compute map (t<250): 4 cols x 1 row
  int y = y0 + r;
  bool rok[3];
  #pragma unroll
  for (int rr=0; rr<3; ++rr) rok[rr] = (unsigned)(y-1+rr) < 200u;
  bool xl = (cg>0), xr = (cg<49);

  float acc[3][4];
  #pragma unroll
  for (int oc=0;oc<3;++oc){
    float bz = cb[oc];
    #pragma unroll
    for (int c=0;c<4;++c) acc[oc][c] = bz;
  }

  auto STAGE = [&](int buf, int p){        // stage channel pair p (2p, 2p+1)
    const float* cp = cbase0 + p*80000;
    #pragma unroll
    for (int j=0;j<3;++j){
      int k = wv + 4*j;
      const float* g = cp + goff[j];
#if __has_builtin(__builtin_amdgcn_global_load_lds)
      __builtin_amdgcn_global_load_lds(
          (const __attribute__((address_space(1))) void*)g,
          (__attribute__((address_space(3))) void*)&sbuf[buf][k*256], 16, 0, 0);
#else
      *(float4*)&sbuf[buf][(k*64 + lane)*4] = *(const float4*)g;
#endif
    }
  };

  STAGE(0, 0);
  for (int p=0; p<6; ++p){
    int cur = p & 1;
    if (p < 5){
      STAGE(cur^1, p+1);
      asm volatile("s_waitcnt vmcnt(3)" ::: "memory");
    } else {
      asm volatile("s_waitcnt vmcnt(0)" ::: "memory");
    }
    __builtin_amdgcn_s_barrier();
    if (t < 250){
      #pragma unroll
      for (int cc=0; cc<2; ++cc){
        float vr[3][6];
        #pragma unroll
        for (int rr=0; rr<3; ++rr){
          const float* rp = &sbuf[cur][cc*1400 + (r+rr)*200 + 4*cg];
          if (rok[rr]){
            float4 m = *(const float4*)rp;
            vr[rr][0] = xl ? rp[-1] : 0.f;
            vr[rr][1] = m.x; vr[rr][2] = m.y; vr[rr][3] = m.z; vr[rr][4] = m.w;
            vr[rr][5] = xr ? rp[4] : 0.f;
          } else {
            #pragma unroll
            for (int q=0;q<6;++q) vr[rr][q] = 0.f;
          }
        }
        int ci = 2*p + cc;
        #pragma unroll
        for (int oc=0;oc<3;++oc){
          const float* wp = cw + oc*108 + ci*9;
          float w00=wp[0], w01=wp[1], w02=wp[2],
                w10=wp[3], w11=wp[4], w12=wp[5],
                w20=wp[6], w21=wp[7], w22=wp[8];
          #pragma unroll
          for (int c=0;c<4;++c){
            float s = acc[oc][c];
            s = fmaf(vr[0][c+0], w00, s); s = fmaf(vr[0][c+1], w01, s); s = fmaf(vr[0][c+2], w02, s);
            s = fmaf(vr[1][c+0], w10, s); s = fmaf(vr[1][c+1], w11, s); s = fmaf(vr[1][c+2], w12, s);
            s = fmaf(vr[2][c+0], w20, s); s = fmaf(vr[2][c+1], w21, s); s = fmaf(vr[2][c+2], w22, s);
            acc[oc][c] = s;
          }
        }
      }
    }
    __builtin_amdgcn_s_barrier();
  }

  if (t < 250){
    f16* ob = c1h + (size_t)b*120000;
    #pragma unroll
    for (int oc=0;oc<3;++oc){
      f16x4 w4;
      #pragma unroll
      for (int c=0;c<4;++c) w4[c] = (f16)acc[oc][c];
      *(f16x4*)(ob + oc*40000 + y*200 + 4*cg) = w4;
    }
  }
}

// ------------- conv2: 3->32, 3x3, s2 (f16 in) + relu + partial mean -------------
__global__ __launch_bounds__(256) void k_conv2(const f16* __restrict__ c1h,
    const float* __restrict__ w2, const float* __restrict__ b2,
    float* __restrict__ part){
  int b = blockIdx.y, ty = blockIdx.x;     // ty 0..19 -> 5 output rows
  int t = threadIdx.x, lane = t&63, wv = t>>6;
  __shared__ __align__(16) f16 z[6656];    // 832 float4 slots (825 used)
  const f16* cbs = c1h + (size_t)b*120000;

  #pragma unroll
  for (int j=0;j<4;++j){
    int k = wv + 4*j;                      // chunk 0..15
    int e = k*64 + lane;
    if (e < 825){
      int ci = e/275, rem = e - 275*ci;    // 275 float4 per channel (11 rows x 25)
      int lr = rem/25, c8 = (rem - 25*lr)*8;
      int gy = 10*ty - 1 + lr; if (gy < 0) gy = 0;   // clamp; masked at compute
      const f16* g = cbs + ci*40000 + gy*200 + c8;
#if __has_builtin(__builtin_amdgcn_global_load_lds)
      __builtin_amdgcn_global_load_lds(
          (const __attribute__((address_space(1))) void*)g,
          (__attribute__((address_space(3))) void*)&z[k*512], 16, 0, 0);
#else
      *(float4*)&z[e*8] = *(const float4*)g;
#endif
    }
  }
  __syncthreads();

  float acc[32];
  #pragma unroll
  for (int co=0;co<32;++co) acc[co]=0.f;
  if (t < 250){
    int r = t/50;                          // local oy 0..4
    int g = t%50;                          // out cols 2g,2g+1; taps cols 4g-1..4g+3
    bool xl = (g>0);
    float vr[3][3][5];
    #pragma unroll
    for (int ci=0;ci<3;++ci){
      #pragma unroll
      for (int ky=0;ky<3;++ky){
        int s = 2*r + ky;                  // staged row 0..10
        bool rok = (10*ty + 2*r + ky - 1) >= 0;      // only ty=0,r=0,ky=0 invalid
        const f16* rp = &z[ci*2200 + s*200 + 4*g];
        if (rok){
          f16x4 m = *(const f16x4*)rp;
          vr[ci][ky][0] = xl ? (float)rp[-1] : 0.f;
          vr[ci][ky][1] = (float)m[0]; vr[ci][ky][2] = (float)m[1];
          vr[ci][ky][3] = (float)m[2]; vr[ci][ky][4] = (float)m[3];
        } else {
          #pragma unroll
          for (int q=0;q<5;++q) vr[ci][ky][q] = 0.f;
        }
      }
    }
    #pragma unroll
    for (int c=0;c<2;++c){
      #pragma unroll
      for (int co=0;co<32;++co){
        float s = b2[co];
        #pragma unroll
        for (int ci=0;ci<3;++ci)
          #pragma unroll
          for (int ky=0;ky<3;++ky)
            #pragma unroll
            for (int kx=0;kx<3;++kx)
              s = fmaf(vr[ci][ky][2*c+kx], w2[co*27+ci*9+ky*3+kx], s);
        acc[co] += fmaxf(s, 0.f);
      }
    }
  }
  __shared__ float wred[4][32];
  #pragma unroll
  for (int co=0;co<32;++co){
    float s = acc[co];
    #pragma unroll
    for (int off=32; off; off>>=1) s += __shfl_down(s, off, 64);
    if (lane==0) wred[wv][co] = s;
  }
  __syncthreads();
  if (t < 32){
    float s = wred[0][t]+wred[1][t]+wred[2][t]+wred[3][t];
    part[(b*20+ty)*32 + t] = s;
  }
}

// ------------- LSTM with inline fc (const4) prologue; 1 block per batch -------------
__global__ __launch_bounds__(256) void k_lstm(
    const float* __restrict__ hist_pts, const float* __restrict__ hist_step,
    const float* __restrict__ emb_w, const float* __restrict__ emb_b,
    const float* __restrict__ h0, const float* __restrict__ c0,
    const float* __restrict__ w_ih, const float* __restrict__ w_hh,
    const float* __restrict__ b_ih, const float* __restrict__ b_hh,
    const float* __restrict__ out_w, const float* __restrict__ out_b,
    const float* __restrict__ part, const float* __restrict__ fcw,
    const float* __restrict__ fcb, float* __restrict__ traj){
  int b = blockIdx.x; int t = threadIdx.x; int lane = t&63, wv = t>>6;

  __shared__ float zfc[32];
  __shared__ float wredfc[4][4];
  if (t < 32){
    float s = 0.f;
    #pragma unroll
    for (int p=0;p<20;++p) s += part[(b*20+p)*32 + t];
    zfc[t] = s * (1.f/10000.f);
  }
  __syncthreads();
  {
    float cp0=0.f, cp1=0.f, cp2=0.f, cp3=0.f;
    for (int o = t; o < 1000; o += 256){
      float s = fcb[o];
      #pragma unroll
      for (int k=0;k<32;++k) s = fmaf(fcw[o*32+k], zfc[k], s);
      cp0 = fmaf(s, out_w[0*1128+128+o], cp0);
      cp1 = fmaf(s, out_w[1*1128+128+o], cp1);
      cp2 = fmaf(s, out_w[2*1128+128+o], cp2);
      cp3 = fmaf(s, out_w[3*1128+128+o], cp3);
    }
    #pragma unroll
    for (int off=32; off; off>>=1){
      cp0 += __shfl_down(cp0, off, 64);
      cp1 += __shfl_down(cp1, off, 64);
      cp2 += __shfl_down(cp2, off, 64);
      cp3 += __shfl_down(cp3, off, 64);
    }
    if (lane==0){ wredfc[wv][0]=cp0; wredfc[wv][1]=cp1; wredfc[wv][2]=cp2; wredfc[wv][3]=cp3; }
  }
  __syncthreads();
  float cst = 0.f;
  if (t < 4) cst = out_b[t] + wredfc[0][t]+wredfc[1][t]+wredfc[2][t]+wredfc[3][t];

  int u  = (t<128) ? t       : t-128;
  int j1 = (t<128) ? t       : 128+u;
  int j2 = (t<128) ? 256+t   : 384+u;

  f16x2 w1[96], w2[96];
  {
    const float2* r1 = (const float2*)(w_ih + j1*64);
    const float2* r2 = (const float2*)(w_ih + j2*64);
    #pragma unroll
    for (int p=0;p<32;++p){
      float2 a = r1[p], c = r2[p];
      w1[p] = f16x2{(f16)a.x, (f16)a.y};
      w2[p] = f16x2{(f16)c.x, (f16)c.y};
    }
    const float2* q1 = (const float2*)(w_hh + j1*128);
    const float2* q2 = (const float2*)(w_hh + j2*128);
    #pragma unroll
    for (int p=0;p<64;++p){
      float2 a = q1[p], c = q2[p];
      w1[32+p] = f16x2{(f16)a.x, (f16)a.y};
      w2[32+p] = f16x2{(f16)c.x, (f16)c.y};
    }
  }
  float bias1 = b_ih[j1] + b_hh[j1];
  float bias2 = b_ih[j2] + b_hh[j2];

  __shared__ f16x2 xl[96];
  __shared__ float e_lds[64], h_lds[128], a_lds[128];
  __shared__ float step_lds[4], wred4[4];

  float c_reg = (t>=128) ? c0[u] : 0.f;
  if (t < 128) h_lds[t] = h0[t];

  auto cell = [&](){
    __syncthreads();
    if (t < 32)      xl[t]    = f16x2{(f16)e_lds[2*t],        (f16)e_lds[2*t+1]};
    else if (t < 96){ int p=t-32; xl[t] = f16x2{(f16)h_lds[2*p], (f16)h_lds[2*p+1]}; }
    __syncthreads();
    float acc1 = bias1, acc2 = bias2;
    #pragma unroll
    for (int cc=0; cc<12; ++cc){
      f16x2 xv[8];
      #pragma unroll
      for (int q=0;q<8;++q) xv[q] = xl[cc*8+q];
      #pragma unroll
      for (int q=0;q<8;++q){
        acc1 = dot2acc(w1[cc*8+q], xv[q], acc1);
        acc2 = dot2acc(w2[cc*8+q], xv[q], acc2);
      }
    }
    if (t < 128){
      float ig = 1.f/(1.f+expf(-acc1));
      float gg = tanhf(acc2);
      a_lds[t] = ig*gg;
    }
    __syncthreads();
    if (t >= 128){
      float ff = 1.f/(1.f+expf(-acc1));
      float oo = 1.f/(1.f+expf(-acc2));
      c_reg = ff*c_reg + a_lds[u];
      h_lds[u] = oo * tanhf(c_reg);
    }
  };

  for (int s=1; s<10; ++s){
    if (t < 64){
      const float* hp = hist_step + (size_t)(b*10+s)*4;
      float e = emb_b[t]
              + emb_w[t*4+0]*hp[0] + emb_w[t*4+1]*hp[1]
              + emb_w[t*4+2]*hp[2] + emb_w[t*4+3]*hp[3];
      e_lds[t] = fmaxf(e, 0.f);
    }
    cell();
  }

  float pose = (t<4) ? hist_pts[(size_t)(b*10+9)*4 + t] : 0.f;
  for (int it=0; it<10; ++it){
    __syncthreads();
    {
      const float* owr = out_w + wv*1128;
      float p_ = owr[2*lane]*h_lds[2*lane] + owr[2*lane+1]*h_lds[2*lane+1];
      #pragma unroll
      for (int off=32; off; off>>=1) p_ += __shfl_down(p_, off, 64);
      if (lane==0) wred4[wv] = p_;
    }
    __syncthreads();
    if (t < 4){
      float st = wred4[t] + cst;
      pose += st;
      traj[(size_t)(b*10+it)*4 + t] = pose;
      step_lds[t] = st;
    }
    __syncthreads();
    if (it < 9){
      if (t < 64){
        float e = emb_b[t]
                + emb_w[t*4+0]*step_lds[0] + emb_w[t*4+1]*step_lds[1]
                + emb_w[t*4+2]*step_lds[2] + emb_w[t*4+3]*step_lds[3];
        e_lds[t] = fmaxf(e, 0.f);
      }
      cell();
    }
  }
}

// ------------- rasterizer: max of 3 isotropic gaussians = exp(-min d^2 / (2 s^2)) -------------
__global__ __launch_bounds__(256) void k_raster(const float* __restrict__ traj,
    const float* __restrict__ ego, float* __restrict__ boxes){
  int img = blockIdx.y;
  int b = img / 10;
  __shared__ float ctr[6];
  if (threadIdx.x == 0){
    float x  = traj[img*4+0];
    float y  = traj[img*4+1];
    float hd = traj[img*4+2];
    float eg = ego[b];
    float ho = 1.5707963267948966f - eg;
    float sho, cho; __sincosf(ho, &sho, &cho);
    float pxc = 100.f + (x*cho - y*sho)*10.f;
    float pyc = 160.f - (x*sho + y*cho)*10.f;
    float bh  = -hd - eg;
    float sbh, cbh; __sincosf(bh, &sbh, &cbh);
    const float CSH = 14.235f;
    const float FSH = 28.47f;
    ctr[0] = pxc;             ctr[1] = pyc;
    ctr[2] = pxc + CSH*cbh;   ctr[3] = pyc - CSH*sbh;
    ctr[4] = pxc + FSH*cbh;   ctr[5] = pyc - FSH*sbh;
  }
  __syncthreads();
  int f4 = blockIdx.x*256 + threadIdx.x;
  if (f4 >= 10000) return;
  int p0 = f4*4;
  int i = p0 / 200;
  int j = p0 % 200;
  float fi = (float)i, fj = (float)j;
  float c0x=ctr[0], c0y=ctr[1], c1x=ctr[2], c1y=ctr[3], c2x=ctr[4], c2y=ctr[5];
  float dx0 = fi-c0x, dx1 = fi-c1x, dx2 = fi-c2x;
  float A0 = dx0*dx0, A1 = dx1*dx1, A2 = dx2*dx2;
  const float GA = 0.15432098765432098f;
  float r[4];
  #pragma unroll
  for (int l=0;l<4;++l){
    float dj = fj + (float)l;
    float dy0 = dj-c0y, dy1 = dj-c1y, dy2 = dj-c2y;
    float d0 = fmaf(dy0,dy0,A0);
    float d1 = fmaf(dy1,dy1,A1);
    float d2 = fmaf(dy2,dy2,A2);
    float m = fminf(d0, fminf(d1,d2));
    r[l] = __expf(-m*GA);
  }
  *(float4*)(boxes + (size_t)img*40000 + p0) = make_float4(r[0],r[1],r[2],r[3]);
}

extern "C" void kernel_launch(void* const* d_in, const int* in_sizes, int n_in,
                              void* d_out, int out_size, void* d_ws, size_t ws_size,
                              hipStream_t stream) {
  (void)in_sizes; (void)n_in; (void)d_ws; (void)ws_size; (void)out_size;
  const float* img = (const float*)d_in[0];
  const float* hp  = (const float*)d_in[1];
  const float* hps = (const float*)d_in[2];
  const float* ego = (const float*)d_in[3];
  const float* cw  = (const float*)d_in[4];
  const float* cb  = (const float*)d_in[5];
  const float* c2w = (const float*)d_in[6];
  const float* c2b = (const float*)d_in[7];
  const float* fcw = (const float*)d_in[8];
  const float* fcb = (const float*)d_in[9];
  const float* ew  = (const float*)d_in[10];
  const float* eb  = (const float*)d_in[11];
  const float* h0  = (const float*)d_in[12];
  const float* c0  = (const float*)d_in[13];
  const float* wih = (const float*)d_in[14];
  const float* whh = (const float*)d_in[15];
  const float* bih = (const float*)d_in[16];
  const float* bhh = (const float*)d_in[17];
  const float* ow  = (const float*)d_in[18];
  const float* ob  = (const float*)d_in[19];

  float* out  = (float*)d_out;
  float* traj = out;                 // (64,10,4)
  float* S    = out + 2560;          // boxes region doubles as scratch until k_raster
  float* part = S;                   // 64*20*32 floats
  f16*   c1h  = (f16*)(S + 50000);   // 64*3*200*200 f16 = 15.36 MB

  // MEASUREMENT ROUND: conv1 launched twice (idempotent). Delta vs R19's 138.2us
  // total == conv1's marginal duration. Decision rule in journal.
  hipLaunchKernelGGL(k_conv1, dim3(40, 64), dim3(256), 0, stream, img, cw, cb, c1h);
  hipLaunchKernelGGL(k_conv1, dim3(40, 64), dim3(256), 0, stream, img, cw, cb, c1h);
  hipLaunchKernelGGL(k_conv2, dim3(20, 64), dim3(256), 0, stream, c1h, c2w, c2b, part);
  hipLaunchKernelGGL(k_lstm,  dim3(64),     dim3(256), 0, stream,
                     hp, hps, ew, eb, h0, c0, wih, whh, bih, bhh, ow, ob, part, fcw, fcb, traj);
  hipLaunchKernelGGL(k_raster, dim3(40, 640), dim3(256), 0, stream, traj, ego, S);
}

// Round 21
// 133.463 us; speedup vs baseline: 1.3230x; 1.3230x over previous
//
#include <hip/hip_runtime.h>
#include <math.h>

typedef _Float16 f16;
typedef f16 f16x2 __attribute__((ext_vector_type(2)));
typedef f16 f16x4 __attribute__((ext_vector_type(4)));

__device__ __forceinline__ float dot2acc(f16x2 a, f16x2 b, float c){
#if __has_builtin(__builtin_amdgcn_fdot2)
  return __builtin_amdgcn_fdot2(a, b, c, false);
#else
  return c + (float)a[0]*(float)b[0] + (float)a[1]*(float)b[1];
#endif
}

__device__ __forceinline__ f16x2 pk2(float a, float b){
#if __has_builtin(__builtin_amdgcn_cvt_pkrtz)
  auto h = __builtin_amdgcn_cvt_pkrtz(a, b);
  return *(f16x2*)&h;
#else
  return f16x2{(f16)a, (f16)b};
#endif
}

union U4 { uint4 u; f16x2 h[4]; };

// ---------------- conv1: 12->3, 3x3, s1, SAME -> c1 (f16) ----------------
// v8: f16x2 channel-pair packing. Per round (channel pair 2p,2p+1): reg-stage
// 4 coalesced float4 loads/thread, cvt_pkrtz -> f16x2 pairs, 1 ds_write_b128;
// compute with v_dot2 (halves VALU) reading 1 LDS word per pixel-pair (halves
// LDS insts). Double-buffered; 1 raw barrier/round, lgkmcnt-only (no vmcnt
// drain -> prefetch survives). LDS 11.2 KB.
__global__ __launch_bounds__(256) void k_conv1(const float* __restrict__ img,
    const float* __restrict__ cw, const float* __restrict__ cb,
    f16* __restrict__ c1h){
  int b = blockIdx.y, ty = blockIdx.x;     // ty 0..39 -> rows [5ty,5ty+5)
  int t = threadIdx.x;
  int y0 = ty*5;

  __shared__ __align__(16) f16x2 sb[2][1408];   // 2 x (7 rows x 200 px pairs)

  // slots: 350 = 7 rows x 50 col-groups (4 px). thread t: slot t (+slot t+256 if t<94)
  bool has1 = (t < 94);
  int e1 = t + 256;
  int lr0 = t/50,  c40 = t%50;
  int lr1 = e1/50, c41 = e1%50;
  int gy0 = y0 - 1 + lr0; gy0 = gy0<0?0:(gy0>199?199:gy0);
  int gy1 = y0 - 1 + lr1; gy1 = gy1<0?0:(gy1>199?199:gy1);
  int off0 = gy0*200 + c40*4;
  int off1 = gy1*200 + c41*4;
  int l0 = lr0*200 + c40*4;
  int l1 = lr1*200 + c41*4;
  const float* cb0 = img + (size_t)b*480000;

  int cg = t % 50, r = t / 50;             // compute map (t<250): 4 cols x 1 row
  int y = y0 + r;
  bool act = (t < 250);
  bool rok[3];
  #pragma unroll
  for (int rr=0; rr<3; ++rr) rok[rr] = (unsigned)(y-1+rr) < 200u;
  bool xl = (cg>0), xr = (cg<49);
  const f16x2 z2 = f16x2{(f16)0.f,(f16)0.f};

  float acc[3][4];
  #pragma unroll
  for (int oc=0;oc<3;++oc){
    float bz = cb[oc];
    #pragma unroll
    for (int c=0;c<4;++c) acc[oc][c] = bz;
  }

  float4 A0 = make_float4(0,0,0,0), A1 = A0, B0 = A0, B1 = A0;
  {
    const float* cp = cb0;                 // round 0: channels 0,1
    A0 = *(const float4*)(cp + off0); A1 = *(const float4*)(cp + 40000 + off0);
    if (has1){ B0 = *(const float4*)(cp + off1); B1 = *(const float4*)(cp + 40000 + off1); }
  }

  #pragma unroll
  for (int p=0; p<6; ++p){
    float4 cA0=A0, cA1=A1, cB0=B0, cB1=B1;
    if (p < 5){
      const float* cp = cb0 + (p+1)*80000;
      A0 = *(const float4*)(cp + off0); A1 = *(const float4*)(cp + 40000 + off0);
      if (has1){ B0 = *(const float4*)(cp + off1); B1 = *(const float4*)(cp + 40000 + off1); }
    }
    f16x2* dst = sb[p & 1];
    {
      U4 w0;
      w0.h[0]=pk2(cA0.x,cA1.x); w0.h[1]=pk2(cA0.y,cA1.y);
      w0.h[2]=pk2(cA0.z,cA1.z); w0.h[3]=pk2(cA0.w,cA1.w);
      *(uint4*)&dst[l0] = w0.u;
      if (has1){
        U4 w1;
        w1.h[0]=pk2(cB0.x,cB1.x); w1.h[1]=pk2(cB0.y,cB1.y);
        w1.h[2]=pk2(cB0.z,cB1.z); w1.h[3]=pk2(cB0.w,cB1.w);
        *(uint4*)&dst[l1] = w1.u;
      }
    }
    asm volatile("s_waitcnt lgkmcnt(0)" ::: "memory");
    __builtin_amdgcn_s_barrier();          // buf[p&1] fully written

    if (act){
      // pack weights for channel pair (2p, 2p+1)
      f16x2 wpk[3][9];
      #pragma unroll
      for (int oc=0;oc<3;++oc)
        #pragma unroll
        for (int k=0;k<9;++k)
          wpk[oc][k] = pk2(cw[oc*108 + (2*p)*9 + k], cw[oc*108 + (2*p+1)*9 + k]);

      f16x2 vp[3][6];
      #pragma unroll
      for (int rr=0; rr<3; ++rr){
        const f16x2* rp = &dst[(r+rr)*200 + 4*cg];
        if (rok[rr]){
          U4 q; q.u = *(const uint4*)rp;
          vp[rr][0] = xl ? rp[-1] : z2;
          vp[rr][1] = q.h[0]; vp[rr][2] = q.h[1];
          vp[rr][3] = q.h[2]; vp[rr][4] = q.h[3];
          vp[rr][5] = xr ? rp[4] : z2;
        } else {
          #pragma unroll
          for (int q2=0;q2<6;++q2) vp[rr][q2] = z2;
        }
      }
      #pragma unroll
      for (int oc=0;oc<3;++oc){
        #pragma unroll
        for (int c=0;c<4;++c){
          float s = acc[oc][c];
          #pragma unroll
          for (int ky=0;ky<3;++ky){
            s = dot2acc(wpk[oc][ky*3+0], vp[ky][c+0], s);
            s = dot2acc(wpk[oc][ky*3+1], vp[ky][c+1], s);
            s = dot2acc(wpk[oc][ky*3+2], vp[ky][c+2], s);
          }
          acc[oc][c] = s;
        }
      }
    }
    // no trailing barrier: next round writes the OTHER buffer; re-write of this
    // buffer (round p+2) is gated by round p+1's barrier.
  }

  if (act){
    f16* ob = c1h + (size_t)b*120000;
    #pragma unroll
    for (int oc=0;oc<3;++oc){
      f16x4 w4;
      #pragma unroll
      for (int c=0;c<4;++c) w4[c] = (f16)acc[oc][c];
      *(f16x4*)(ob + oc*40000 + y*200 + 4*cg) = w4;
    }
  }
}

// ------------- conv2: 3->32, 3x3, s2 (f16 in) + relu + partial mean -------------
__global__ __launch_bounds__(256) void k_conv2(const f16* __restrict__ c1h,
    const float* __restrict__ w2, const float* __restrict__ b2,
    float* __restrict__ part){
  int b = blockIdx.y, ty = blockIdx.x;     // ty 0..19 -> 5 output rows
  int t = threadIdx.x, lane = t&63, wv = t>>6;
  __shared__ __align__(16) f16 z[6656];    // 832 float4 slots (825 used)
  const f16* cbs = c1h + (size_t)b*120000;

  #pragma unroll
  for (int j=0;j<4;++j){
    int k = wv + 4*j;                      // chunk 0..15
    int e = k*64 + lane;
    if (e < 825){
      int ci = e/275, rem = e - 275*ci;    // 275 float4 per channel (11 rows x 25)
      int lr = rem/25, c8 = (rem - 25*lr)*8;
      int gy = 10*ty - 1 + lr; if (gy < 0) gy = 0;   // clamp; masked at compute
      const f16* g = cbs + ci*40000 + gy*200 + c8;
#if __has_builtin(__builtin_amdgcn_global_load_lds)
      __builtin_amdgcn_global_load_lds(
          (const __attribute__((address_space(1))) void*)g,
          (__attribute__((address_space(3))) void*)&z[k*512], 16, 0, 0);
#else
      *(float4*)&z[e*8] = *(const float4*)g;
#endif
    }
  }
  __syncthreads();

  float acc[32];
  #pragma unroll
  for (int co=0;co<32;++co) acc[co]=0.f;
  if (t < 250){
    int r = t/50;                          // local oy 0..4
    int g = t%50;                          // out cols 2g,2g+1; taps cols 4g-1..4g+3
    bool xl = (g>0);
    float vr[3][3][5];
    #pragma unroll
    for (int ci=0;ci<3;++ci){
      #pragma unroll
      for (int ky=0;ky<3;++ky){
        int s = 2*r + ky;                  // staged row 0..10
        bool rok = (10*ty + 2*r + ky - 1) >= 0;      // only ty=0,r=0,ky=0 invalid
        const f16* rp = &z[ci*2200 + s*200 + 4*g];
        if (rok){
          f16x4 m = *(const f16x4*)rp;
          vr[ci][ky][0] = xl ? (float)rp[-1] : 0.f;
          vr[ci][ky][1] = (float)m[0]; vr[ci][ky][2] = (float)m[1];
          vr[ci][ky][3] = (float)m[2]; vr[ci][ky][4] = (float)m[3];
        } else {
          #pragma unroll
          for (int q=0;q<5;++q) vr[ci][ky][q] = 0.f;
        }
      }
    }
    #pragma unroll
    for (int c=0;c<2;++c){
      #pragma unroll
      for (int co=0;co<32;++co){
        float s = b2[co];
        #pragma unroll
        for (int ci=0;ci<3;++ci)
          #pragma unroll
          for (int ky=0;ky<3;++ky)
            #pragma unroll
            for (int kx=0;kx<3;++kx)
              s = fmaf(vr[ci][ky][2*c+kx], w2[co*27+ci*9+ky*3+kx], s);
        acc[co] += fmaxf(s, 0.f);
      }
    }
  }
  __shared__ float wred[4][32];
  #pragma unroll
  for (int co=0;co<32;++co){
    float s = acc[co];
    #pragma unroll
    for (int off=32; off; off>>=1) s += __shfl_down(s, off, 64);
    if (lane==0) wred[wv][co] = s;
  }
  __syncthreads();
  if (t < 32){
    float s = wred[0][t]+wred[1][t]+wred[2][t]+wred[3][t];
    part[(b*20+ty)*32 + t] = s;
  }
}

// ------------- LSTM with inline fc (const4) prologue; 1 block per batch -------------
__global__ __launch_bounds__(256) void k_lstm(
    const float* __restrict__ hist_pts, const float* __restrict__ hist_step,
    const float* __restrict__ emb_w, const float* __restrict__ emb_b,
    const float* __restrict__ h0, const float* __restrict__ c0,
    const float* __restrict__ w_ih, const float* __restrict__ w_hh,
    const float* __restrict__ b_ih, const float* __restrict__ b_hh,
    const float* __restrict__ out_w, const float* __restrict__ out_b,
    const float* __restrict__ part, const float* __restrict__ fcw,
    const float* __restrict__ fcb, float* __restrict__ traj){
  int b = blockIdx.x; int t = threadIdx.x; int lane = t&63, wv = t>>6;

  __shared__ float zfc[32];
  __shared__ float wredfc[4][4];
  if (t < 32){
    float s = 0.f;
    #pragma unroll
    for (int p=0;p<20;++p) s += part[(b*20+p)*32 + t];
    zfc[t] = s * (1.f/10000.f);
  }
  __syncthreads();
  {
    float cp0=0.f, cp1=0.f, cp2=0.f, cp3=0.f;
    for (int o = t; o < 1000; o += 256){
      float s = fcb[o];
      #pragma unroll
      for (int k=0;k<32;++k) s = fmaf(fcw[o*32+k], zfc[k], s);
      cp0 = fmaf(s, out_w[0*1128+128+o], cp0);
      cp1 = fmaf(s, out_w[1*1128+128+o], cp1);
      cp2 = fmaf(s, out_w[2*1128+128+o], cp2);
      cp3 = fmaf(s, out_w[3*1128+128+o], cp3);
    }
    #pragma unroll
    for (int off=32; off; off>>=1){
      cp0 += __shfl_down(cp0, off, 64);
      cp1 += __shfl_down(cp1, off, 64);
      cp2 += __shfl_down(cp2, off, 64);
      cp3 += __shfl_down(cp3, off, 64);
    }
    if (lane==0){ wredfc[wv][0]=cp0; wredfc[wv][1]=cp1; wredfc[wv][2]=cp2; wredfc[wv][3]=cp3; }
  }
  __syncthreads();
  float cst = 0.f;
  if (t < 4) cst = out_b[t] + wredfc[0][t]+wredfc[1][t]+wredfc[2][t]+wredfc[3][t];

  int u  = (t<128) ? t       : t-128;
  int j1 = (t<128) ? t       : 128+u;
  int j2 = (t<128) ? 256+t   : 384+u;

  f16x2 w1[96], w2[96];
  {
    const float2* r1 = (const float2*)(w_ih + j1*64);
    const float2* r2 = (const float2*)(w_ih + j2*64);
    #pragma unroll
    for (int p=0;p<32;++p){
      float2 a = r1[p], c = r2[p];
      w1[p] = f16x2{(f16)a.x, (f16)a.y};
      w2[p] = f16x2{(f16)c.x, (f16)c.y};
    }
    const float2* q1 = (const float2*)(w_hh + j1*128);
    const float2* q2 = (const float2*)(w_hh + j2*128);
    #pragma unroll
    for (int p=0;p<64;++p){
      float2 a = q1[p], c = q2[p];
      w1[32+p] = f16x2{(f16)a.x, (f16)a.y};
      w2[32+p] = f16x2{(f16)c.x, (f16)c.y};
    }
  }
  float bias1 = b_ih[j1] + b_hh[j1];
  float bias2 = b_ih[j2] + b_hh[j2];

  __shared__ f16x2 xl[96];
  __shared__ float e_lds[64], h_lds[128], a_lds[128];
  __shared__ float step_lds[4], wred4[4];

  float c_reg = (t>=128) ? c0[u] : 0.f;
  if (t < 128) h_lds[t] = h0[t];

  auto cell = [&](){
    __syncthreads();
    if (t < 32)      xl[t]    = f16x2{(f16)e_lds[2*t],        (f16)e_lds[2*t+1]};
    else if (t < 96){ int p=t-32; xl[t] = f16x2{(f16)h_lds[2*p], (f16)h_lds[2*p+1]}; }
    __syncthreads();
    float acc1 = bias1, acc2 = bias2;
    #pragma unroll
    for (int cc=0; cc<12; ++cc){
      f16x2 xv[8];
      #pragma unroll
      for (int q=0;q<8;++q) xv[q] = xl[cc*8+q];
      #pragma unroll
      for (int q=0;q<8;++q){
        acc1 = dot2acc(w1[cc*8+q], xv[q], acc1);
        acc2 = dot2acc(w2[cc*8+q], xv[q], acc2);
      }
    }
    if (t < 128){
      float ig = 1.f/(1.f+expf(-acc1));
      float gg = tanhf(acc2);
      a_lds[t] = ig*gg;
    }
    __syncthreads();
    if (t >= 128){
      float ff = 1.f/(1.f+expf(-acc1));
      float oo = 1.f/(1.f+expf(-acc2));
      c_reg = ff*c_reg + a_lds[u];
      h_lds[u] = oo * tanhf(c_reg);
    }
  };

  for (int s=1; s<10; ++s){
    if (t < 64){
      const float* hp = hist_step + (size_t)(b*10+s)*4;
      float e = emb_b[t]
              + emb_w[t*4+0]*hp[0] + emb_w[t*4+1]*hp[1]
              + emb_w[t*4+2]*hp[2] + emb_w[t*4+3]*hp[3];
      e_lds[t] = fmaxf(e, 0.f);
    }
    cell();
  }

  float pose = (t<4) ? hist_pts[(size_t)(b*10+9)*4 + t] : 0.f;
  for (int it=0; it<10; ++it){
    __syncthreads();
    {
      const float* owr = out_w + wv*1128;
      float p_ = owr[2*lane]*h_lds[2*lane] + owr[2*lane+1]*h_lds[2*lane+1];
      #pragma unroll
      for (int off=32; off; off>>=1) p_ += __shfl_down(p_, off, 64);
      if (lane==0) wred4[wv] = p_;
    }
    __syncthreads();
    if (t < 4){
      float st = wred4[t] + cst;
      pose += st;
      traj[(size_t)(b*10+it)*4 + t] = pose;
      step_lds[t] = st;
    }
    __syncthreads();
    if (it < 9){
      if (t < 64){
        float e = emb_b[t]
                + emb_w[t*4+0]*step_lds[0] + emb_w[t*4+1]*step_lds[1]
                + emb_w[t*4+2]*step_lds[2] + emb_w[t*4+3]*step_lds[3];
        e_lds[t] = fmaxf(e, 0.f);
      }
      cell();
    }
  }
}

// ------------- rasterizer: max of 3 isotropic gaussians = exp(-min d^2 / (2 s^2)) -------------
__global__ __launch_bounds__(256) void k_raster(const float* __restrict__ traj,
    const float* __restrict__ ego, float* __restrict__ boxes){
  int img = blockIdx.y;
  int b = img / 10;
  __shared__ float ctr[6];
  if (threadIdx.x == 0){
    float x  = traj[img*4+0];
    float y  = traj[img*4+1];
    float hd = traj[img*4+2];
    float eg = ego[b];
    float ho = 1.5707963267948966f - eg;
    float sho, cho; __sincosf(ho, &sho, &cho);
    float pxc = 100.f + (x*cho - y*sho)*10.f;
    float pyc = 160.f - (x*sho + y*cho)*10.f;
    float bh  = -hd - eg;
    float sbh, cbh; __sincosf(bh, &sbh, &cbh);
    const float CSH = 14.235f;
    const float FSH = 28.47f;
    ctr[0] = pxc;             ctr[1] = pyc;
    ctr[2] = pxc + CSH*cbh;   ctr[3] = pyc - CSH*sbh;
    ctr[4] = pxc + FSH*cbh;   ctr[5] = pyc - FSH*sbh;
  }
  __syncthreads();
  int f4 = blockIdx.x*256 + threadIdx.x;
  if (f4 >= 10000) return;
  int p0 = f4*4;
  int i = p0 / 200;
  int j = p0 % 200;
  float fi = (float)i, fj = (float)j;
  float c0x=ctr[0], c0y=ctr[1], c1x=ctr[2], c1y=ctr[3], c2x=ctr[4], c2y=ctr[5];
  float dx0 = fi-c0x, dx1 = fi-c1x, dx2 = fi-c2x;
  float A0 = dx0*dx0, A1 = dx1*dx1, A2 = dx2*dx2;
  const float GA = 0.15432098765432098f;
  float r[4];
  #pragma unroll
  for (int l=0;l<4;++l){
    float dj = fj + (float)l;
    float dy0 = dj-c0y, dy1 = dj-c1y, dy2 = dj-c2y;
    float d0 = fmaf(dy0,dy0,A0);
    float d1 = fmaf(dy1,dy1,A1);
    float d2 = fmaf(dy2,dy2,A2);
    float m = fminf(d0, fminf(d1,d2));
    r[l] = __expf(-m*GA);
  }
  *(float4*)(boxes + (size_t)img*40000 + p0) = make_float4(r[0],r[1],r[2],r[3]);
}

extern "C" void kernel_launch(void* const* d_in, const int* in_sizes, int n_in,
                              void* d_out, int out_size, void* d_ws, size_t ws_size,
                              hipStream_t stream) {
  (void)in_sizes; (void)n_in; (void)d_ws; (void)ws_size; (void)out_size;
  const float* img = (const float*)d_in[0];
  const float* hp  = (const float*)d_in[1];
  const float* hps = (const float*)d_in[2];
  const float* ego = (const float*)d_in[3];
  const float* cw  = (const float*)d_in[4];
  const float* cb  = (const float*)d_in[5];
  const float* c2w = (const float*)d_in[6];
  const float* c2b = (const float*)d_in[7];
  const float* fcw = (const float*)d_in[8];
  const float* fcb = (const float*)d_in[9];
  const float* ew  = (const float*)d_in[10];
  const float* eb  = (const float*)d_in[11];
  const float* h0  = (const float*)d_in[12];
  const float* c0  = (const float*)d_in[13];
  const float* wih = (const float*)d_in[14];
  const float* whh = (const float*)d_in[15];
  const float* bih = (const float*)d_in[16];
  const float* bhh = (const float*)d_in[17];
  const float* ow  = (const float*)d_in[18];
  const float* ob  = (const float*)d_in[19];

  float* out  = (float*)d_out;
  float* traj = out;                 // (64,10,4)
  float* S    = out + 2560;          // boxes region doubles as scratch until k_raster
  float* part = S;                   // 64*20*32 floats
  f16*   c1h  = (f16*)(S + 50000);   // 64*3*200*200 f16 = 15.36 MB

  hipLaunchKernelGGL(k_conv1, dim3(40, 64), dim3(256), 0, stream, img, cw, cb, c1h);
  hipLaunchKernelGGL(k_conv2, dim3(20, 64), dim3(256), 0, stream, c1h, c2w, c2b, part);
  hipLaunchKernelGGL(k_lstm,  dim3(64),     dim3(256), 0, stream,
                     hp, hps, ew, eb, h0, c0, wih, whh, bih, bhh, ow, ob, part, fcw, fcb, traj);
  hipLaunchKernelGGL(k_raster, dim3(40, 640), dim3(256), 0, stream, traj, ego, S);
}

// Round 22
// 130.698 us; speedup vs baseline: 1.3510x; 1.0212x over previous
//
#include <hip/hip_runtime.h>
#include <math.h>

typedef _Float16 f16;
typedef f16 f16x2 __attribute__((ext_vector_type(2)));
typedef f16 f16x4 __attribute__((ext_vector_type(4)));

__device__ __forceinline__ float dot2acc(f16x2 a, f16x2 b, float c){
#if __has_builtin(__builtin_amdgcn_fdot2)
  return __builtin_amdgcn_fdot2(a, b, c, false);
#else
  return c + (float)a[0]*(float)b[0] + (float)a[1]*(float)b[1];
#endif
}

__device__ __forceinline__ f16x2 pk2(float a, float b){
#if __has_builtin(__builtin_amdgcn_cvt_pkrtz)
  auto h = __builtin_amdgcn_cvt_pkrtz(a, b);
  return *(f16x2*)&h;
#else
  return f16x2{(f16)a, (f16)b};
#endif
}

union U4 { uint4 u; f16x2 h[4]; };

// ---------------- conv1: 12->3, 3x3, s1, SAME -> c1 (f16) ----------------
// v9: 10-row bands (halo 1.2x vs 1.4x) + f16x2 channel-pair packing + dot2.
// Per round (ch pair 2p,2p+1): reg-prefetch coalesced float4s, cvt_pkrtz ->
// f16x2, ds_write_b128; 1 raw barrier/round (lgkmcnt only). 2 out rows/thread.
__global__ __launch_bounds__(256) void k_conv1(const float* __restrict__ img,
    const float* __restrict__ cw, const float* __restrict__ cb,
    f16* __restrict__ c1h){
  int b = blockIdx.y, ty = blockIdx.x;     // ty 0..19 -> rows [10ty,10ty+10)
  int t = threadIdx.x;
  int y0 = ty*10;

  __shared__ __align__(16) f16x2 sb[2][2400];   // 2 x (12 rows x 200 px pairs)

  // staging: 600 uint4 slots (12 rows x 50 col-groups); thread t: e = t, t+256, t+512(<600)
  int off[3], lofs[3]; bool hs[3];
  #pragma unroll
  for (int j=0;j<3;++j){
    int e = t + 256*j;
    hs[j] = (e < 600);
    int ec = hs[j] ? e : 599;
    int lr = ec/50, c4 = ec%50;
    int gy = y0 - 1 + lr; gy = gy<0?0:(gy>199?199:gy);
    off[j]  = gy*200 + c4*4;
    lofs[j] = lr*200 + c4*4;
  }
  const float* cb0 = img + (size_t)b*480000;

  int cg = t % 50, rt = t / 50;            // compute map (t<250): 4 cols x 2 rows
  bool act = (t < 250);
  bool rok[4];
  #pragma unroll
  for (int rr=0; rr<4; ++rr){
    int gy = y0 - 1 + 2*rt + rr;
    rok[rr] = (unsigned)gy < 200u;
  }
  bool xl = (cg>0), xr = (cg<49);
  const f16x2 z2 = f16x2{(f16)0.f,(f16)0.f};

  float acc[3][2][4];
  #pragma unroll
  for (int oc=0;oc<3;++oc){
    float bz = cb[oc];
    #pragma unroll
    for (int j=0;j<2;++j)
      #pragma unroll
      for (int c=0;c<4;++c) acc[oc][j][c] = bz;
  }

  float4 P0[3], P1[3];
  #pragma unroll
  for (int j=0;j<3;++j){
    P0[j] = make_float4(0,0,0,0); P1[j] = P0[j];
    if (hs[j]){ P0[j] = *(const float4*)(cb0 + off[j]); P1[j] = *(const float4*)(cb0 + 40000 + off[j]); }
  }

  #pragma unroll
  for (int p=0; p<6; ++p){
    float4 c0_[3], c1_[3];
    #pragma unroll
    for (int j=0;j<3;++j){ c0_[j]=P0[j]; c1_[j]=P1[j]; }
    if (p < 5){
      const float* cp = cb0 + (p+1)*80000;
      #pragma unroll
      for (int j=0;j<3;++j){
        if (hs[j]){ P0[j] = *(const float4*)(cp + off[j]); P1[j] = *(const float4*)(cp + 40000 + off[j]); }
      }
    }
    f16x2* dst = sb[p & 1];
    #pragma unroll
    for (int j=0;j<3;++j){
      if (hs[j]){
        U4 w;
        w.h[0]=pk2(c0_[j].x,c1_[j].x); w.h[1]=pk2(c0_[j].y,c1_[j].y);
        w.h[2]=pk2(c0_[j].z,c1_[j].z); w.h[3]=pk2(c0_[j].w,c1_[j].w);
        *(uint4*)&dst[lofs[j]] = w.u;
      }
    }
    asm volatile("s_waitcnt lgkmcnt(0)" ::: "memory");
    __builtin_amdgcn_s_barrier();          // buf[p&1] fully written

    if (act){
      f16x2 wpk[3][9];
      #pragma unroll
      for (int oc=0;oc<3;++oc)
        #pragma unroll
        for (int k=0;k<9;++k)
          wpk[oc][k] = pk2(cw[oc*108 + (2*p)*9 + k], cw[oc*108 + (2*p+1)*9 + k]);

      f16x2 vp[4][6];
      #pragma unroll
      for (int rr=0; rr<4; ++rr){
        const f16x2* rp = &dst[(2*rt+rr)*200 + 4*cg];
        if (rok[rr]){
          U4 q; q.u = *(const uint4*)rp;
          vp[rr][0] = xl ? rp[-1] : z2;
          vp[rr][1] = q.h[0]; vp[rr][2] = q.h[1];
          vp[rr][3] = q.h[2]; vp[rr][4] = q.h[3];
          vp[rr][5] = xr ? rp[4] : z2;
        } else {
          #pragma unroll
          for (int q2=0;q2<6;++q2) vp[rr][q2] = z2;
        }
      }
      #pragma unroll
      for (int oc=0;oc<3;++oc){
        #pragma unroll
        for (int j=0;j<2;++j){
          #pragma unroll
          for (int c=0;c<4;++c){
            float s = acc[oc][j][c];
            #pragma unroll
            for (int ky=0;ky<3;++ky){
              s = dot2acc(wpk[oc][ky*3+0], vp[j+ky][c+0], s);
              s = dot2acc(wpk[oc][ky*3+1], vp[j+ky][c+1], s);
              s = dot2acc(wpk[oc][ky*3+2], vp[j+ky][c+2], s);
            }
            acc[oc][j][c] = s;
          }
        }
      }
    }
  }

  if (act){
    f16* ob = c1h + (size_t)b*120000;
    int y = y0 + 2*rt;
    #pragma unroll
    for (int oc=0;oc<3;++oc){
      #pragma unroll
      for (int j=0;j<2;++j){
        f16x4 w4;
        #pragma unroll
        for (int c=0;c<4;++c) w4[c] = (f16)acc[oc][j][c];
        *(f16x4*)(ob + oc*40000 + (y+j)*200 + 4*cg) = w4;
      }
    }
  }
}

// ------------- conv2: 3->32, 3x3, s2 (f16 in) + relu + partial mean -------------
__global__ __launch_bounds__(256) void k_conv2(const f16* __restrict__ c1h,
    const float* __restrict__ w2, const float* __restrict__ b2,
    float* __restrict__ part){
  int b = blockIdx.y, ty = blockIdx.x;     // ty 0..19 -> 5 output rows
  int t = threadIdx.x, lane = t&63, wv = t>>6;
  __shared__ __align__(16) f16 z[6656];    // 832 float4 slots (825 used)
  const f16* cbs = c1h + (size_t)b*120000;

  #pragma unroll
  for (int j=0;j<4;++j){
    int k = wv + 4*j;                      // chunk 0..15
    int e = k*64 + lane;
    if (e < 825){
      int ci = e/275, rem = e - 275*ci;    // 275 float4 per channel (11 rows x 25)
      int lr = rem/25, c8 = (rem - 25*lr)*8;
      int gy = 10*ty - 1 + lr; if (gy < 0) gy = 0;   // clamp; masked at compute
      const f16* g = cbs + ci*40000 + gy*200 + c8;
#if __has_builtin(__builtin_amdgcn_global_load_lds)
      __builtin_amdgcn_global_load_lds(
          (const __attribute__((address_space(1))) void*)g,
          (__attribute__((address_space(3))) void*)&z[k*512], 16, 0, 0);
#else
      *(float4*)&z[e*8] = *(const float4*)g;
#endif
    }
  }
  __syncthreads();

  float acc[32];
  #pragma unroll
  for (int co=0;co<32;++co) acc[co]=0.f;
  if (t < 250){
    int r = t/50;                          // local oy 0..4
    int g = t%50;                          // out cols 2g,2g+1; taps cols 4g-1..4g+3
    bool xl = (g>0);
    float vr[3][3][5];
    #pragma unroll
    for (int ci=0;ci<3;++ci){
      #pragma unroll
      for (int ky=0;ky<3;++ky){
        int s = 2*r + ky;                  // staged row 0..10
        bool rok = (10*ty + 2*r + ky - 1) >= 0;      // only ty=0,r=0,ky=0 invalid
        const f16* rp = &z[ci*2200 + s*200 + 4*g];
        if (rok){
          f16x4 m = *(const f16x4*)rp;
          vr[ci][ky][0] = xl ? (float)rp[-1] : 0.f;
          vr[ci][ky][1] = (float)m[0]; vr[ci][ky][2] = (float)m[1];
          vr[ci][ky][3] = (float)m[2]; vr[ci][ky][4] = (float)m[3];
        } else {
          #pragma unroll
          for (int q=0;q<5;++q) vr[ci][ky][q] = 0.f;
        }
      }
    }
    #pragma unroll
    for (int c=0;c<2;++c){
      #pragma unroll
      for (int co=0;co<32;++co){
        float s = b2[co];
        #pragma unroll
        for (int ci=0;ci<3;++ci)
          #pragma unroll
          for (int ky=0;ky<3;++ky)
            #pragma unroll
            for (int kx=0;kx<3;++kx)
              s = fmaf(vr[ci][ky][2*c+kx], w2[co*27+ci*9+ky*3+kx], s);
        acc[co] += fmaxf(s, 0.f);
      }
    }
  }
  __shared__ float wred[4][32];
  #pragma unroll
  for (int co=0;co<32;++co){
    float s = acc[co];
    #pragma unroll
    for (int off=32; off; off>>=1) s += __shfl_down(s, off, 64);
    if (lane==0) wred[wv][co] = s;
  }
  __syncthreads();
  if (t < 32){
    float s = wred[0][t]+wred[1][t]+wred[2][t]+wred[3][t];
    part[(b*20+ty)*32 + t] = s;
  }
}

// ------------- LSTM with inline fc (const4) prologue; 1 block per batch -------------
__global__ __launch_bounds__(256) void k_lstm(
    const float* __restrict__ hist_pts, const float* __restrict__ hist_step,
    const float* __restrict__ emb_w, const float* __restrict__ emb_b,
    const float* __restrict__ h0, const float* __restrict__ c0,
    const float* __restrict__ w_ih, const float* __restrict__ w_hh,
    const float* __restrict__ b_ih, const float* __restrict__ b_hh,
    const float* __restrict__ out_w, const float* __restrict__ out_b,
    const float* __restrict__ part, const float* __restrict__ fcw,
    const float* __restrict__ fcb, float* __restrict__ traj){
  int b = blockIdx.x; int t = threadIdx.x; int lane = t&63, wv = t>>6;

  __shared__ float zfc[32];
  __shared__ float wredfc[4][4];
  if (t < 32){
    float s = 0.f;
    #pragma unroll
    for (int p=0;p<20;++p) s += part[(b*20+p)*32 + t];
    zfc[t] = s * (1.f/10000.f);
  }
  __syncthreads();
  {
    float cp0=0.f, cp1=0.f, cp2=0.f, cp3=0.f;
    for (int o = t; o < 1000; o += 256){
      float s = fcb[o];
      #pragma unroll
      for (int k=0;k<32;++k) s = fmaf(fcw[o*32+k], zfc[k], s);
      cp0 = fmaf(s, out_w[0*1128+128+o], cp0);
      cp1 = fmaf(s, out_w[1*1128+128+o], cp1);
      cp2 = fmaf(s, out_w[2*1128+128+o], cp2);
      cp3 = fmaf(s, out_w[3*1128+128+o], cp3);
    }
    #pragma unroll
    for (int off=32; off; off>>=1){
      cp0 += __shfl_down(cp0, off, 64);
      cp1 += __shfl_down(cp1, off, 64);
      cp2 += __shfl_down(cp2, off, 64);
      cp3 += __shfl_down(cp3, off, 64);
    }
    if (lane==0){ wredfc[wv][0]=cp0; wredfc[wv][1]=cp1; wredfc[wv][2]=cp2; wredfc[wv][3]=cp3; }
  }
  __syncthreads();
  float cst = 0.f;
  if (t < 4) cst = out_b[t] + wredfc[0][t]+wredfc[1][t]+wredfc[2][t]+wredfc[3][t];

  int u  = (t<128) ? t       : t-128;
  int j1 = (t<128) ? t       : 128+u;
  int j2 = (t<128) ? 256+t   : 384+u;

  f16x2 w1[96], w2[96];
  {
    const float2* r1 = (const float2*)(w_ih + j1*64);
    const float2* r2 = (const float2*)(w_ih + j2*64);
    #pragma unroll
    for (int p=0;p<32;++p){
      float2 a = r1[p], c = r2[p];
      w1[p] = f16x2{(f16)a.x, (f16)a.y};
      w2[p] = f16x2{(f16)c.x, (f16)c.y};
    }
    const float2* q1 = (const float2*)(w_hh + j1*128);
    const float2* q2 = (const float2*)(w_hh + j2*128);
    #pragma unroll
    for (int p=0;p<64;++p){
      float2 a = q1[p], c = q2[p];
      w1[32+p] = f16x2{(f16)a.x, (f16)a.y};
      w2[32+p] = f16x2{(f16)c.x, (f16)c.y};
    }
  }
  float bias1 = b_ih[j1] + b_hh[j1];
  float bias2 = b_ih[j2] + b_hh[j2];

  __shared__ f16x2 xl[96];
  __shared__ float e_lds[64], h_lds[128], a_lds[128];
  __shared__ float step_lds[4], wred4[4];

  float c_reg = (t>=128) ? c0[u] : 0.f;
  if (t < 128) h_lds[t] = h0[t];

  auto cell = [&](){
    __syncthreads();
    if (t < 32)      xl[t]    = f16x2{(f16)e_lds[2*t],        (f16)e_lds[2*t+1]};
    else if (t < 96){ int p=t-32; xl[t] = f16x2{(f16)h_lds[2*p], (f16)h_lds[2*p+1]}; }
    __syncthreads();
    float acc1 = bias1, acc2 = bias2;
    #pragma unroll
    for (int cc=0; cc<12; ++cc){
      f16x2 xv[8];
      #pragma unroll
      for (int q=0;q<8;++q) xv[q] = xl[cc*8+q];
      #pragma unroll
      for (int q=0;q<8;++q){
        acc1 = dot2acc(w1[cc*8+q], xv[q], acc1);
        acc2 = dot2acc(w2[cc*8+q], xv[q], acc2);
      }
    }
    if (t < 128){
      float ig = 1.f/(1.f+expf(-acc1));
      float gg = tanhf(acc2);
      a_lds[t] = ig*gg;
    }
    __syncthreads();
    if (t >= 128){
      float ff = 1.f/(1.f+expf(-acc1));
      float oo = 1.f/(1.f+expf(-acc2));
      c_reg = ff*c_reg + a_lds[u];
      h_lds[u] = oo * tanhf(c_reg);
    }
  };

  for (int s=1; s<10; ++s){
    if (t < 64){
      const float* hp = hist_step + (size_t)(b*10+s)*4;
      float e = emb_b[t]
              + emb_w[t*4+0]*hp[0] + emb_w[t*4+1]*hp[1]
              + emb_w[t*4+2]*hp[2] + emb_w[t*4+3]*hp[3];
      e_lds[t] = fmaxf(e, 0.f);
    }
    cell();
  }

  float pose = (t<4) ? hist_pts[(size_t)(b*10+9)*4 + t] : 0.f;
  for (int it=0; it<10; ++it){
    __syncthreads();
    {
      const float* owr = out_w + wv*1128;
      float p_ = owr[2*lane]*h_lds[2*lane] + owr[2*lane+1]*h_lds[2*lane+1];
      #pragma unroll
      for (int off=32; off; off>>=1) p_ += __shfl_down(p_, off, 64);
      if (lane==0) wred4[wv] = p_;
    }
    __syncthreads();
    if (t < 4){
      float st = wred4[t] + cst;
      pose += st;
      traj[(size_t)(b*10+it)*4 + t] = pose;
      step_lds[t] = st;
    }
    __syncthreads();
    if (it < 9){
      if (t < 64){
        float e = emb_b[t]
                + emb_w[t*4+0]*step_lds[0] + emb_w[t*4+1]*step_lds[1]
                + emb_w[t*4+2]*step_lds[2] + emb_w[t*4+3]*step_lds[3];
        e_lds[t] = fmaxf(e, 0.f);
      }
      cell();
    }
  }
}

// ------------- rasterizer: max of 3 isotropic gaussians = exp(-min d^2 / (2 s^2)) -------------
__global__ __launch_bounds__(256) void k_raster(const float* __restrict__ traj,
    const float* __restrict__ ego, float* __restrict__ boxes){
  int img = blockIdx.y;
  int b = img / 10;
  __shared__ float ctr[6];
  if (threadIdx.x == 0){
    float x  = traj[img*4+0];
    float y  = traj[img*4+1];
    float hd = traj[img*4+2];
    float eg = ego[b];
    float ho = 1.5707963267948966f - eg;
    float sho, cho; __sincosf(ho, &sho, &cho);
    float pxc = 100.f + (x*cho - y*sho)*10.f;
    float pyc = 160.f - (x*sho + y*cho)*10.f;
    float bh  = -hd - eg;
    float sbh, cbh; __sincosf(bh, &sbh, &cbh);
    const float CSH = 14.235f;
    const float FSH = 28.47f;
    ctr[0] = pxc;             ctr[1] = pyc;
    ctr[2] = pxc + CSH*cbh;   ctr[3] = pyc - CSH*sbh;
    ctr[4] = pxc + FSH*cbh;   ctr[5] = pyc - FSH*sbh;
  }
  __syncthreads();
  int f4 = blockIdx.x*256 + threadIdx.x;
  if (f4 >= 10000) return;
  int p0 = f4*4;
  int i = p0 / 200;
  int j = p0 % 200;
  float fi = (float)i, fj = (float)j;
  float c0x=ctr[0], c0y=ctr[1], c1x=ctr[2], c1y=ctr[3], c2x=ctr[4], c2y=ctr[5];
  float dx0 = fi-c0x, dx1 = fi-c1x, dx2 = fi-c2x;
  float A0 = dx0*dx0, A1 = dx1*dx1, A2 = dx2*dx2;
  const float GA = 0.15432098765432098f;
  float r[4];
  #pragma unroll
  for (int l=0;l<4;++l){
    float dj = fj + (float)l;
    float dy0 = dj-c0y, dy1 = dj-c1y, dy2 = dj-c2y;
    float d0 = fmaf(dy0,dy0,A0);
    float d1 = fmaf(dy1,dy1,A1);
    float d2 = fmaf(dy2,dy2,A2);
    float m = fminf(d0, fminf(d1,d2));
    r[l] = __expf(-m*GA);
  }
  *(float4*)(boxes + (size_t)img*40000 + p0) = make_float4(r[0],r[1],r[2],r[3]);
}

extern "C" void kernel_launch(void* const* d_in, const int* in_sizes, int n_in,
                              void* d_out, int out_size, void* d_ws, size_t ws_size,
                              hipStream_t stream) {
  (void)in_sizes; (void)n_in; (void)d_ws; (void)ws_size; (void)out_size;
  const float* img = (const float*)d_in[0];
  const float* hp  = (const float*)d_in[1];
  const float* hps = (const float*)d_in[2];
  const float* ego = (const float*)d_in[3];
  const float* cw  = (const float*)d_in[4];
  const float* cb  = (const float*)d_in[5];
  const float* c2w = (const float*)d_in[6];
  const float* c2b = (const float*)d_in[7];
  const float* fcw = (const float*)d_in[8];
  const float* fcb = (const float*)d_in[9];
  const float* ew  = (const float*)d_in[10];
  const float* eb  = (const float*)d_in[11];
  const float* h0  = (const float*)d_in[12];
  const float* c0  = (const float*)d_in[13];
  const float* wih = (const float*)d_in[14];
  const float* whh = (const float*)d_in[15];
  const float* bih = (const float*)d_in[16];
  const float* bhh = (const float*)d_in[17];
  const float* ow  = (const float*)d_in[18];
  const float* ob  = (const float*)d_in[19];

  float* out  = (float*)d_out;
  float* traj = out;                 // (64,10,4)
  float* S    = out + 2560;          // boxes region doubles as scratch until k_raster
  float* part = S;                   // 64*20*32 floats
  f16*   c1h  = (f16*)(S + 50000);   // 64*3*200*200 f16 = 15.36 MB

  hipLaunchKernelGGL(k_conv1, dim3(20, 64), dim3(256), 0, stream, img, cw, cb, c1h);
  hipLaunchKernelGGL(k_conv2, dim3(20, 64), dim3(256), 0, stream, c1h, c2w, c2b, part);
  hipLaunchKernelGGL(k_lstm,  dim3(64),     dim3(256), 0, stream,
                     hp, hps, ew, eb, h0, c0, wih, whh, bih, bhh, ow, ob, part, fcw, fcb, traj);
  hipLaunchKernelGGL(k_raster, dim3(40, 640), dim3(256), 0, stream, traj, ego, S);
}